// Round 7
// baseline (297.542 us; speedup 1.0000x reference)
//
#include <hip/hip_runtime.h>
#include <hip/hip_bf16.h>

// Problem constants
#define BATCH 16
#define IN_C 3
#define Q_C 8
#define V_C 16
#define HH 224
#define WW 224
#define KK 7

// Padded layouts
#define XPH 230   // plane row = orig x row + 3
#define QPH 118
#define QPW 120

// Region sizes (elements)
#define PLANES_N (BATCH*7*IN_C*XPH*QPW)        // 9,273,600 bf16
#define VPAD_N   (BATCH*V_C*QPH*QPW)           // 3,624,960 f32
#define QPADS_STRIDE (Q_C*4*QPH*QPW)           // 453,120 per (b,ic)
#define QPADS_N  (BATCH*IN_C*QPADS_STRIDE)     // 21,749,760 bf16
#define D_N      (BATCH*IN_C*128*160)          // 983,040 f32
#define A_N      (BATCH*IN_C*V_C*16)
#define OUT_N    (BATCH*IN_C*58*58)

typedef __attribute__((ext_vector_type(8))) short bf16x8;
typedef __attribute__((ext_vector_type(4))) float f32x4;

static __device__ inline unsigned short f2b(float f) {
    __hip_bfloat16 h = __float2bfloat16(f);
    return *reinterpret_cast<unsigned short*>(&h);
}

// ---------------- Kernel X: dx-deinterleaved bf16 planes of x ----------------
// planes[b][dx][ci][row][k] = x[row-3][2k+dx-3] (zero outside), row<230, k<120
__global__ __launch_bounds__(256) void kX(const float* __restrict__ x,
                                          unsigned short* __restrict__ planes) {
    int idx = blockIdx.x * 256 + threadIdx.x;
    if (idx >= PLANES_N) return;
    int k = idx % QPW;
    int t = idx / QPW;
    int row = t % XPH; t /= XPH;
    int ci = t % IN_C; t /= IN_C;
    int dx = t % 7;
    int b  = t / 7;
    int r = row - 3;
    int c = 2 * k + dx - 3;
    float val = 0.0f;
    if (r >= 0 && r < HH && c >= 0 && c < WW)
        val = x[((size_t)(b * IN_C + ci) * HH + r) * WW + c];
    planes[idx] = f2b(val);
}

// ---------------- Kernel QV: q conv (-> qpadS bf16 shift-copies) + v conv ----
// Reads x from bf16 planes (kills kP/xpad): x[2y+dy-3][2(8seg+j)+dx-3]
//   = planes[b][dx][ci][2y+dy][8seg+j]; one uint4 load feeds 4ch*8 = 32 FMAs.
__global__ __launch_bounds__(256) void kQV(const unsigned short* __restrict__ planes,
                                           const float* __restrict__ Wq,
                                           const float* __restrict__ bq,
                                           const float* __restrict__ Wv,
                                           const float* __restrict__ bv,
                                           unsigned short* __restrict__ qpadS,
                                           float* __restrict__ vpad) {
    int blk = blockIdx.x;               // b*70 + pb*10 + grp
    int grp = blk % 10;
    int t2  = blk / 10;
    int pb  = t2 % 7;
    int b   = t2 / 7;
    int tid = threadIdx.x;

    __shared__ float wlds[4 * IN_C * KK * 8];   // [cc][ci][dy][dx pad 8]
    __shared__ float bsh[4];

    if (tid < 84) {
        int cc = tid / 21, rest = tid % 21;
        int ch = 4 * grp + cc;
        const float* wsrc = (ch < 24) ? (Wq + (size_t)ch * 147)
                                      : (Wv + (size_t)(ch - 24) * 147);
        #pragma unroll
        for (int dx = 0; dx < 7; ++dx) wlds[tid * 8 + dx] = wsrc[rest * 7 + dx];
        wlds[tid * 8 + 7] = 0.0f;
    }
    if (tid < 4) {
        int ch = 4 * grp + tid;
        bsh[tid] = (ch < 24) ? bq[ch] : bv[ch - 24];
    }
    __syncthreads();

    int pos = pb * 256 + tid;
    if (pos >= 112 * 14) return;
    int y   = pos / 14;
    int seg = pos - y * 14;

    float kv[4][8];
    #pragma unroll
    for (int cc = 0; cc < 4; ++cc)
        #pragma unroll
        for (int j = 0; j < 8; ++j) kv[cc][j] = bsh[cc];

    for (int ci = 0; ci < IN_C; ++ci) {
        for (int dy = 0; dy < KK; ++dy) {
            int absrow = 2 * y + dy;
            float wv_[4][8];
            #pragma unroll
            for (int cc = 0; cc < 4; ++cc) {
                const float* wbase = &wlds[((cc * IN_C + ci) * KK + dy) * 8];
                *(float4*)&wv_[cc][0] = ((const float4*)wbase)[0];
                *(float4*)&wv_[cc][4] = ((const float4*)wbase)[1];
            }
            #pragma unroll
            for (int dx = 0; dx < 7; ++dx) {
                const unsigned short* src = planes
                    + (((size_t)(b * 7 + dx) * IN_C + ci) * XPH + absrow) * QPW + 8 * seg;
                uint4 rv = *(const uint4*)src;
                float xf[8];
                xf[0] = __uint_as_float(rv.x << 16);
                xf[1] = __uint_as_float(rv.x & 0xFFFF0000u);
                xf[2] = __uint_as_float(rv.y << 16);
                xf[3] = __uint_as_float(rv.y & 0xFFFF0000u);
                xf[4] = __uint_as_float(rv.z << 16);
                xf[5] = __uint_as_float(rv.z & 0xFFFF0000u);
                xf[6] = __uint_as_float(rv.w << 16);
                xf[7] = __uint_as_float(rv.w & 0xFFFF0000u);
                #pragma unroll
                for (int cc = 0; cc < 4; ++cc)
                    #pragma unroll
                    for (int j = 0; j < 8; ++j)
                        kv[cc][j] = fmaf(wv_[cc][dx], xf[j], kv[cc][j]);
            }
        }
    }

    int row = y + 3, c0 = 8 * seg + 3;
    if (grp < 6) {
        #pragma unroll
        for (int cc = 0; cc < 4; ++cc) {
            int ch = 4 * grp + cc;
            int icq = ch >> 3, qc = ch & 7;
            unsigned short* base = qpadS + (size_t)(b * IN_C + icq) * QPADS_STRIDE
                                 + (size_t)qc * 4 * QPH * QPW;
            #pragma unroll
            for (int tw = 0; tw < 4; ++tw) {
                unsigned short* bp = base + (tw * QPH + row) * QPW;
                #pragma unroll
                for (int j = 0; j < 8; ++j) {
                    int k = c0 + j - 2 * tw;
                    if (k >= 0) bp[k] = f2b(kv[cc][j]);
                }
            }
        }
    } else {
        #pragma unroll
        for (int cc = 0; cc < 4; ++cc) {
            int vc = 4 * grp + cc - 24;
            float* op = vpad + (((size_t)(b * V_C + vc)) * QPH + row) * QPW + c0;
            #pragma unroll
            for (int j = 0; j < 8; ++j) op[j] = kv[cc][j];
        }
    }
}

// ---------------- Kernel C: MFMA GEMM with rolling ring-buffer B ----------------
// Block = (b, yc). 512 thr / 8 waves, M=384 shared-B. LDS: 21 planes x 8-row
// ring (slot = plane-row & 7) + ones row. Per ry only 2 new plane rows are
// staged (~9 KB, prefetched to regs before MFMA, written after), vs 35 KB
// full-tile restaging in R6. Two barriers per ry guard slot reuse.
__global__ __launch_bounds__(512, 2) void kC(const unsigned short* __restrict__ planes,
                                             const unsigned short* __restrict__ qpadS,
                                             float* __restrict__ D) {
    int blk = blockIdx.x;
    int b  = blk & 15;
    int yc = blk >> 4;
    int tid = threadIdx.x;
    int w = tid >> 6, lane = tid & 63;
    int tt = lane & 15, kq = lane >> 4;
    int th = tt >> 2, tw = tt & 3;

    __shared__ uint4 smem[169 * 17];   // (21 planes x 8 rows + ones) x 136 bf16

    // zero k-pad chunks 14..16 of every row (k in [112,136) must be 0)
    if (tid < 169 * 3) {
        int r = tid / 3, j = tid % 3;
        smem[r * 17 + 14 + j] = uint4{0, 0, 0, 0};
    }
    // ones row (bf16 1.0)
    if (tid < 14) {
        uint4 o; o.x = o.y = o.z = o.w = 0x3F803F80u;
        smem[168 * 17 + tid] = o;
    }
    // initial stage: ring rows 0..6 = plane rows 16*yc .. 16*yc+6
    #pragma unroll
    for (int i = 0; i < 5; ++i) {
        int c = tid + 512 * i;
        if (c < 21 * 7 * 14) {
            int p   = c / 98;
            int rem = c % 98;
            int rr  = rem / 14;
            int kc  = rem % 14;
            int ci = p / 7, dx = p % 7;
            const unsigned short* src = planes
                + (((size_t)(b * 7 + dx) * IN_C + ci) * XPH + 16 * yc + rr) * QPW + kc * 8;
            smem[(p * 8 + rr) * 17 + kc] = *(const uint4*)src;
        }
    }

    // per-lane B-fragment LDS addressing constants
    int nbase[10], ndy[10], nmsk[10];
    #pragma unroll
    for (int nt = 0; nt < 10; ++nt) {
        int n = nt * 16 + tt;
        if (n < 147) {
            int ci = n / 49, rr = n % 49;
            nbase[nt] = ((ci * 7 + (rr % 7)) * 8) * 17;
            ndy[nt]   = rr / 7;
            nmsk[nt]  = 7;
        } else {
            nbase[nt] = 168 * 17; ndy[nt] = 0; nmsk[nt] = 0;
        }
    }

    const unsigned short* abase[3];
    #pragma unroll
    for (int j = 0; j < 3; ++j) {
        int tile = w * 3 + j;
        int ic = tile >> 3, qc = tile & 7;
        abase[j] = qpadS + (size_t)(b * IN_C + ic) * QPADS_STRIDE
                 + ((qc * 4 + tw) * QPH + 2 * th) * QPW;
    }

    f32x4 acc[3][10];
    #pragma unroll
    for (int j = 0; j < 3; ++j)
        #pragma unroll
        for (int nt = 0; nt < 10; ++nt)
            acc[j][nt] = f32x4{0.f, 0.f, 0.f, 0.f};

    __syncthreads();

    for (int ry = 0; ry < 8; ++ry) {
        int yo = yc * 8 + ry;
        // prefetch next two plane rows (rows 2*yo+7, 2*yo+8) into registers
        uint4 pv0, pv1; int pd0 = -1, pd1 = -1;
        if (ry < 7) {
            {
                int c = tid;                    // 512 < 588: all threads active
                int rn = c / 294, rem = c % 294;
                int p = rem / 14, kc = rem % 14;
                int ci = p / 7, dx = p % 7;
                int absrow = 16 * yc + 2 * ry + 7 + rn;
                pv0 = *(const uint4*)(planes
                    + (((size_t)(b * 7 + dx) * IN_C + ci) * XPH + absrow) * QPW + kc * 8);
                pd0 = (p * 8 + (absrow & 7)) * 17 + kc;
            }
            int c = tid + 512;
            if (c < 588) {
                int rn = c / 294, rem = c % 294;
                int p = rem / 14, kc = rem % 14;
                int ci = p / 7, dx = p % 7;
                int absrow = 16 * yc + 2 * ry + 7 + rn;
                pv1 = *(const uint4*)(planes
                    + (((size_t)(b * 7 + dx) * IN_C + ci) * XPH + absrow) * QPW + kc * 8);
                pd1 = (p * 8 + (absrow & 7)) * 17 + kc;
            }
        }
        int ry2 = 2 * ry;
        #pragma unroll
        for (int s = 0; s < 4; ++s) {
            int k = 32 * s + kq * 8;
            int xs = (k < 112) ? k : 96;       // clamped; multiplies B-zeros
            bf16x8 af[3];
            #pragma unroll
            for (int j = 0; j < 3; ++j)
                af[j] = __builtin_bit_cast(bf16x8,
                    *(const uint4*)(abase[j] + yo * QPW + xs));
            #pragma unroll
            for (int nt = 0; nt < 10; ++nt) {
                bf16x8 bf = __builtin_bit_cast(bf16x8,
                    smem[nbase[nt] + ((ry2 + ndy[nt]) & nmsk[nt]) * 17 + 4 * s + kq]);
                #pragma unroll
                for (int j = 0; j < 3; ++j)
                    acc[j][nt] = __builtin_amdgcn_mfma_f32_16x16x32_bf16(af[j], bf, acc[j][nt], 0, 0, 0);
            }
        }
        __syncthreads();                        // all reads of ring done
        if (pd0 >= 0) smem[pd0] = pv0;
        if (pd1 >= 0) smem[pd1] = pv1;
        __syncthreads();                        // new rows visible
    }

    // epilogue: atomics into D. C/D layout: col = lane&15, row = (lane>>4)*4+reg
    int rowb = kq * 4;
    #pragma unroll
    for (int j = 0; j < 3; ++j) {
        int tile = w * 3 + j;
        int ic = tile >> 3, qc = tile & 7;
        float* Dbi = D + (size_t)(b * IN_C + ic) * (128 * 160);
        int m = qc * 16 + rowb;
        #pragma unroll
        for (int nt = 0; nt < 10; ++nt) {
            int n = nt * 16 + tt;
            if (n < 148) {
                #pragma unroll
                for (int r = 0; r < 4; ++r)
                    atomicAdd(&Dbi[(size_t)(m + r) * 160 + n], acc[j][nt][r]);
            }
        }
    }
}

// ---------------- Kernel E: a[v,t] = sum_{qc,r} Wk*D + sum_qc bk*D[.,147] ----
__global__ __launch_bounds__(256) void kE(const float* __restrict__ D,
                                          const float* __restrict__ Wk,
                                          const float* __restrict__ bk,
                                          float* __restrict__ a_out) {
    int blk = blockIdx.x;              // (b*3+ic)*16 + v
    int bi = blk >> 4;
    int v  = blk & 15;
    int ic = bi % IN_C;
    int tid = threadIdx.x;
    int t  = tid >> 4;
    int rl = tid & 15;
    const float* Dbi = D + (size_t)bi * (128 * 160);
    const float* WkI = Wk + (size_t)(ic * V_C + v) * (Q_C * 147);
    const float* bkI = bk + (ic * V_C + v) * Q_C;
    float s = 0.0f;
    for (int qc = 0; qc < Q_C; ++qc) {
        const float* drow = Dbi + (qc * 16 + t) * 160;
        const float* wrow = WkI + qc * 147;
        #pragma unroll
        for (int j = 0; j < 10; ++j) {
            int r = rl + 16 * j;
            if (r < 147) s = fmaf(wrow[r], drow[r], s);
        }
        if (rl == 0) s = fmaf(bkI[qc], drow[147], s);
    }
    s += __shfl_down(s, 8, 64);
    s += __shfl_down(s, 4, 64);
    s += __shfl_down(s, 2, 64);
    s += __shfl_down(s, 1, 64);
    if (rl == 0) a_out[(size_t)blk * 16 + t] = s;
}

// ---------------- Kernel O: final dynamic conv -> out ----------------
__global__ __launch_bounds__(256) void kO(const float* __restrict__ vpad,
                                          const float* __restrict__ a,
                                          float* __restrict__ out) {
    int idx = blockIdx.x * 256 + threadIdx.x;
    if (idx >= OUT_N) return;
    int ow = idx % 58;
    int t = idx / 58;
    int oh = t % 58; t /= 58;
    int ic = t % IN_C;
    int b  = t / IN_C;
    const float* ab = a + (size_t)(b * IN_C + ic) * (V_C * 16);
    float s = 0.0f;
    for (int vc = 0; vc < V_C; ++vc) {
        const float* vrow = vpad + ((size_t)(b * V_C + vc) * QPH + 2 * oh) * QPW + 2 * ow;
        const float* ar = ab + vc * 16;
        #pragma unroll
        for (int kh = 0; kh < 4; ++kh)
            #pragma unroll
            for (int kw = 0; kw < 4; ++kw)
                s = fmaf(vrow[kh * QPW + kw], ar[kh * 4 + kw], s);
    }
    out[idx] = s;
}

extern "C" void kernel_launch(void* const* d_in, const int* in_sizes, int n_in,
                              void* d_out, int out_size, void* d_ws, size_t ws_size,
                              hipStream_t stream) {
    (void)in_sizes; (void)n_in; (void)out_size; (void)ws_size;
    const float* x  = (const float*)d_in[0];
    const float* Wq = (const float*)d_in[1];
    const float* bq = (const float*)d_in[2];
    const float* Wk = (const float*)d_in[3];
    const float* bk = (const float*)d_in[4];
    const float* Wv = (const float*)d_in[5];
    const float* bv = (const float*)d_in[6];
    float* out = (float*)d_out;

    // ws layout: [planes bf16][vpad f32][qpadS bf16][D f32][a f32]
    char* p = (char*)d_ws;
    unsigned short* planes = (unsigned short*)p;        p += (size_t)PLANES_N * 2;
    float*          vpad   = (float*)p;                 p += (size_t)VPAD_N * 4;
    unsigned short* qpadS  = (unsigned short*)p;        p += (size_t)QPADS_N * 2;
    float*          D      = (float*)p;                 p += (size_t)D_N * 4;
    float*          a      = (float*)p;
    // total ~80.6 MiB

    kX<<<(PLANES_N + 255) / 256, 256, 0, stream>>>(x, planes);
    // zero vpad borders, qpadS borders, D accumulators (contiguous region)
    hipMemsetAsync(vpad, 0,
                   (size_t)VPAD_N * 4 + (size_t)QPADS_N * 2 + (size_t)D_N * 4, stream);
    kQV<<<BATCH * 7 * 10, 256, 0, stream>>>(planes, Wq, bq, Wv, bv, qpadS, vpad);
    kC<<<14 * 16, 512, 0, stream>>>(planes, qpadS, D);
    kE<<<BATCH * IN_C * V_C, 256, 0, stream>>>(D, Wk, bk, a);
    kO<<<(OUT_N + 255) / 256, 256, 0, stream>>>(vpad, a, out);
}